// Round 1
// baseline (609.945 us; speedup 1.0000x reference)
//
#include <hip/hip_runtime.h>
#include <hip/hip_bf16.h>

#define NN 16384
#define DD 256
#define BM 128
#define BN 128
#define BK 64
#define NKS (DD / BK)
#define THREADS 256
#define SHIFT_C 64.0f
#define LOG2E 1.4426950408889634f

typedef __attribute__((ext_vector_type(4))) float f32x4;
typedef __attribute__((ext_vector_type(8))) short bf16x8;

#if __has_builtin(__builtin_amdgcn_exp2f)
#define EXP2F(x) __builtin_amdgcn_exp2f(x)
#else
#define EXP2F(x) exp2f(x)
#endif

__device__ __forceinline__ unsigned pkbf(float a, float b) {
  float2 t; t.x = a; t.y = b;
  __hip_bfloat162 h = __float22bfloat162_rn(t);
  union { __hip_bfloat162 h; unsigned u; } cv;
  cv.h = h;
  return cv.u;
}

__global__ __launch_bounds__(THREADS) void clip_main(
    const float* __restrict__ X, const float* __restrict__ Y,
    float* __restrict__ rowsum, float* __restrict__ colsum,
    float* __restrict__ diagsum) {
  __shared__ __align__(16) unsigned char smem[2 * BM * BK * 2];
  unsigned char* smA = smem;
  unsigned char* smB = smem + BM * BK * 2;

  const int tid = threadIdx.x;
  const int bid = blockIdx.x;
  // XCD-aware swizzle: 16384 blocks, 8 XCDs, 2048 contiguous tiles per XCD
  const int swz = (bid & 7) * 2048 + (bid >> 3);
  const int brow = swz >> 7;
  const int bcol = swz & 127;

  const float* xb = X + (size_t)brow * BM * DD;
  const float* yb = Y + (size_t)bcol * BN * DD;

  const int wid = tid >> 6, lane = tid & 63;
  const int wm = wid >> 1, wn = wid & 1;
  const int lm = lane & 15, lk = lane >> 4;

  f32x4 acc[4][4] = {};

  for (int ks = 0; ks < NKS; ++ks) {
    const int kbase = ks * BK;
    if (ks) __syncthreads();
#pragma unroll
    for (int i = 0; i < 4; ++i) {
      const int c = tid + i * THREADS;
      const int row = c >> 3, slot = c & 7;
      // T2 XOR swizzle: spread the 8 16B slots of each row across banks
      const int boff = row * (BK * 2) + ((slot << 4) ^ ((row & 7) << 4));
      const float* ga = xb + row * DD + kbase + (slot << 3);
      float4 a0 = *(const float4*)ga;
      float4 a1 = *(const float4*)(ga + 4);
      uint4 pa = { pkbf(a0.x, a0.y), pkbf(a0.z, a0.w),
                   pkbf(a1.x, a1.y), pkbf(a1.z, a1.w) };
      *(uint4*)(smA + boff) = pa;
      const float* gb = yb + row * DD + kbase + (slot << 3);
      float4 b0 = *(const float4*)gb;
      float4 b1 = *(const float4*)(gb + 4);
      uint4 pb = { pkbf(b0.x, b0.y), pkbf(b0.z, b0.w),
                   pkbf(b1.x, b1.y), pkbf(b1.z, b1.w) };
      *(uint4*)(smB + boff) = pb;
    }
    __syncthreads();

#pragma unroll
    for (int kk = 0; kk < 2; ++kk) {
      const int kboff = kk * 64 + lk * 16;
      bf16x8 a[4], b[4];
#pragma unroll
      for (int m = 0; m < 4; ++m) {
        const int row = wm * 64 + m * 16 + lm;
        a[m] = *(const bf16x8*)(smA + row * (BK * 2) + (kboff ^ ((row & 7) << 4)));
      }
#pragma unroll
      for (int n = 0; n < 4; ++n) {
        const int row = wn * 64 + n * 16 + lm;
        b[n] = *(const bf16x8*)(smB + row * (BK * 2) + (kboff ^ ((row & 7) << 4)));
      }
#pragma unroll
      for (int m = 0; m < 4; ++m)
#pragma unroll
        for (int n = 0; n < 4; ++n)
          acc[m][n] = __builtin_amdgcn_mfma_f32_16x16x32_bf16(a[m], b[n], acc[m][n], 0, 0, 0);
    }
  }

  // ---- fused softmax-statistics epilogue ----
  float rowacc[4][4];
  float colacc[4];
#pragma unroll
  for (int m = 0; m < 4; ++m)
#pragma unroll
    for (int r = 0; r < 4; ++r) rowacc[m][r] = 0.f;
#pragma unroll
  for (int n = 0; n < 4; ++n) colacc[n] = 0.f;

  const float negC = -(SHIFT_C * LOG2E);
#pragma unroll
  for (int m = 0; m < 4; ++m)
#pragma unroll
    for (int n = 0; n < 4; ++n)
#pragma unroll
      for (int r = 0; r < 4; ++r) {
        float e = EXP2F(__builtin_fmaf(acc[m][n][r], LOG2E, negC));
        rowacc[m][r] += e;
        colacc[n] += e;
      }

  // diagonal logits (only diagonal blocks, only diagonal waves)
  if (brow == bcol && wm == wn) {
    float dsum = 0.f;
#pragma unroll
    for (int m = 0; m < 4; ++m)
#pragma unroll
      for (int n = 0; n < 4; ++n)
#pragma unroll
        for (int r = 0; r < 4; ++r) {
          const int rr = m * 16 + lk * 4 + r;
          const int cc = n * 16 + lm;
          if (rr == cc) dsum += acc[m][n][r];
        }
    dsum += __shfl_xor(dsum, 1);
    dsum += __shfl_xor(dsum, 2);
    dsum += __shfl_xor(dsum, 4);
    dsum += __shfl_xor(dsum, 8);
    dsum += __shfl_xor(dsum, 16);
    dsum += __shfl_xor(dsum, 32);
    if (lane == 0) atomicAdd(diagsum, dsum);
  }

  // row sums: C/D layout row=(lane>>4)*4+reg -> reduce across lane&15
#pragma unroll
  for (int m = 0; m < 4; ++m)
#pragma unroll
    for (int r = 0; r < 4; ++r) {
      float v = rowacc[m][r];
      v += __shfl_xor(v, 1);
      v += __shfl_xor(v, 2);
      v += __shfl_xor(v, 4);
      v += __shfl_xor(v, 8);
      if (lm == 0)
        atomicAdd(&rowsum[brow * BM + wm * 64 + m * 16 + lk * 4 + r], v);
    }
  // col sums: col=lane&15 -> reduce across lane>>4
#pragma unroll
  for (int n = 0; n < 4; ++n) {
    float v = colacc[n];
    v += __shfl_xor(v, 16);
    v += __shfl_xor(v, 32);
    if (lk == 0)
      atomicAdd(&colsum[bcol * BN + wn * 64 + n * 16 + lm], v);
  }
}

__global__ __launch_bounds__(256) void clip_final(
    const float* __restrict__ rowsum, const float* __restrict__ colsum,
    const float* __restrict__ diagsum, float* __restrict__ out) {
  __shared__ double sdata[256];
  double s = 0.0;
  for (int i = threadIdx.x; i < NN; i += 256)
    s += (double)logf(rowsum[i]) + (double)logf(colsum[i]);
  sdata[threadIdx.x] = s;
  __syncthreads();
  for (int st = 128; st > 0; st >>= 1) {
    if ((int)threadIdx.x < st) sdata[threadIdx.x] += sdata[threadIdx.x + st];
    __syncthreads();
  }
  if (threadIdx.x == 0) {
    double loss = (double)SHIFT_C + sdata[0] * 0.5 / (double)NN
                - (double)diagsum[0] / (double)NN;
    out[0] = (float)loss;
  }
}

extern "C" void kernel_launch(void* const* d_in, const int* in_sizes, int n_in,
                              void* d_out, int out_size, void* d_ws, size_t ws_size,
                              hipStream_t stream) {
  const float* X = (const float*)d_in[0];
  const float* Y = (const float*)d_in[1];
  float* rowsum = (float*)d_ws;
  float* colsum = rowsum + NN;
  float* diagsum = colsum + NN;

  hipMemsetAsync(d_ws, 0, (2 * NN + 1) * sizeof(float), stream);

  clip_main<<<dim3((NN / BM) * (NN / BN)), dim3(THREADS), 0, stream>>>(
      X, Y, rowsum, colsum, diagsum);
  clip_final<<<dim3(1), dim3(256), 0, stream>>>(rowsum, colsum, diagsum, (float*)d_out);
}

// Round 2
// 362.783 us; speedup vs baseline: 1.6813x; 1.6813x over previous
//
#include <hip/hip_runtime.h>
#include <hip/hip_bf16.h>

#define NN 16384
#define DD 256
#define BM 128
#define BN 128
#define BK 64
#define NKS (DD / BK)
#define THREADS 256
#define SHIFT_C 64.0f
#define LOG2E 1.4426950408889634f

typedef __attribute__((ext_vector_type(4))) float f32x4;
typedef __attribute__((ext_vector_type(8))) short bf16x8;

#if __has_builtin(__builtin_amdgcn_exp2f)
#define EXP2F(x) __builtin_amdgcn_exp2f(x)
#else
#define EXP2F(x) exp2f(x)
#endif

__device__ __forceinline__ unsigned pkbf(float a, float b) {
  float2 t; t.x = a; t.y = b;
  __hip_bfloat162 h = __float22bfloat162_rn(t);
  union { __hip_bfloat162 h; unsigned u; } cv;
  cv.h = h;
  return cv.u;
}

// ---------------- pre-convert f32 -> bf16 ----------------
__global__ __launch_bounds__(256) void cvt_kernel(
    const float* __restrict__ X, const float* __restrict__ Y,
    unsigned short* __restrict__ Xb, unsigned short* __restrict__ Yb) {
  const int groups_per_arr = NN * DD / 8;  // 524288 groups of 8 elems
  int g = blockIdx.x * 256 + threadIdx.x;
  const float* src;
  unsigned short* dst;
  if (g < groups_per_arr) { src = X; dst = Xb; }
  else { src = Y; dst = Yb; g -= groups_per_arr; }
  float4 a = ((const float4*)src)[(size_t)g * 2];
  float4 b = ((const float4*)src)[(size_t)g * 2 + 1];
  uint4 p = { pkbf(a.x, a.y), pkbf(a.z, a.w), pkbf(b.x, b.y), pkbf(b.z, b.w) };
  ((uint4*)dst)[g] = p;
}

// ---------------- main fused GEMM + softmax-stats (bf16, global_load_lds) ----------------
__global__ __launch_bounds__(THREADS) void clip_gemm(
    const unsigned short* __restrict__ Xb, const unsigned short* __restrict__ Yb,
    float* __restrict__ rowsum, float* __restrict__ colsum,
    float* __restrict__ diagsum) {
  // linear LDS (global_load_lds requires linear dest): A [128][64] bf16, B same
  __shared__ __align__(16) unsigned char smA[BM * BK * 2];
  __shared__ __align__(16) unsigned char smB[BN * BK * 2];

  const int tid = threadIdx.x;
  const int bid = blockIdx.x;
  // 2-level XCD-aware swizzle: each XCD owns brows [16k,16k+16); within XCD,
  // 16x16-tile supertiles so X-slice (2MB) + Y-slice (2MB) are both L2-resident.
  const int xcd = bid & 7;
  const int t = bid >> 3;       // 0..2047 within XCD
  const int st = t >> 8;        // 8 supertiles (column panels of 16 bcols)
  const int idx = t & 255;
  const int brow = xcd * 16 + (idx >> 4);
  const int bcol = st * 16 + (idx & 15);

  const unsigned short* xb = Xb + (size_t)brow * BM * DD;
  const unsigned short* yb = Yb + (size_t)bcol * BN * DD;

  const int wid = tid >> 6, lane = tid & 63;
  const int wm = wid >> 1, wn = wid & 1;
  const int lm = lane & 15, lk = lane >> 4;

  const int srow0 = wid * 8 + (lane >> 3);   // staging row base (per thread)
  const int skoff = (lane & 7) << 3;         // staging k offset (bf16 elems)
  const int sldso = wid * 1024 + lane * 16;  // staging LDS byte offset

  f32x4 acc[4][4] = {};

#define STAGE(ks)                                                              \
  {                                                                            \
    _Pragma("unroll")                                                          \
    for (int i = 0; i < 4; ++i) {                                              \
      const int row = i * 32 + srow0;                                          \
      __builtin_amdgcn_global_load_lds(                                        \
          (const __attribute__((address_space(1))) unsigned*)(xb + (size_t)row * DD + (ks) * BK + skoff), \
          (__attribute__((address_space(3))) unsigned*)(smA + i * 4096 + sldso), 16, 0, 0); \
      __builtin_amdgcn_global_load_lds(                                        \
          (const __attribute__((address_space(1))) unsigned*)(yb + (size_t)row * DD + (ks) * BK + skoff), \
          (__attribute__((address_space(3))) unsigned*)(smB + i * 4096 + sldso), 16, 0, 0); \
    }                                                                          \
  }

  STAGE(0);
  for (int ks = 0; ks < NKS; ++ks) {
    __syncthreads();  // drains vmcnt -> staged tile visible
#pragma unroll
    for (int kk = 0; kk < 2; ++kk) {
      const int kboff = kk * 64 + lk * 16;
      bf16x8 a[4], b[4];
#pragma unroll
      for (int m = 0; m < 4; ++m)
        a[m] = *(const bf16x8*)(smA + (wm * 64 + m * 16 + lm) * (BK * 2) + kboff);
#pragma unroll
      for (int n = 0; n < 4; ++n)
        b[n] = *(const bf16x8*)(smB + (wn * 64 + n * 16 + lm) * (BK * 2) + kboff);
#pragma unroll
      for (int m = 0; m < 4; ++m)
#pragma unroll
        for (int n = 0; n < 4; ++n)
          acc[m][n] = __builtin_amdgcn_mfma_f32_16x16x32_bf16(a[m], b[n], acc[m][n], 0, 0, 0);
    }
    if (ks < NKS - 1) {
      __syncthreads();  // all reads of this tile done before overwrite
      STAGE(ks + 1);
    }
  }
#undef STAGE

  // ---- fused softmax-statistics epilogue ----
  float rowacc[4][4];
  float colacc[4];
#pragma unroll
  for (int m = 0; m < 4; ++m)
#pragma unroll
    for (int r = 0; r < 4; ++r) rowacc[m][r] = 0.f;
#pragma unroll
  for (int n = 0; n < 4; ++n) colacc[n] = 0.f;

  const float negC = -(SHIFT_C * LOG2E);
#pragma unroll
  for (int m = 0; m < 4; ++m)
#pragma unroll
    for (int n = 0; n < 4; ++n)
#pragma unroll
      for (int r = 0; r < 4; ++r) {
        float e = EXP2F(__builtin_fmaf(acc[m][n][r], LOG2E, negC));
        rowacc[m][r] += e;
        colacc[n] += e;
      }

  // diagonal logits (only diagonal blocks, only diagonal waves)
  if (brow == bcol && wm == wn) {
    float dsum = 0.f;
#pragma unroll
    for (int m = 0; m < 4; ++m)
#pragma unroll
      for (int n = 0; n < 4; ++n)
#pragma unroll
        for (int r = 0; r < 4; ++r) {
          const int rr = m * 16 + lk * 4 + r;
          const int cc = n * 16 + lm;
          if (rr == cc) dsum += acc[m][n][r];
        }
    dsum += __shfl_xor(dsum, 1);
    dsum += __shfl_xor(dsum, 2);
    dsum += __shfl_xor(dsum, 4);
    dsum += __shfl_xor(dsum, 8);
    dsum += __shfl_xor(dsum, 16);
    dsum += __shfl_xor(dsum, 32);
    if (lane == 0) atomicAdd(diagsum, dsum);
  }

  // row sums: C/D layout row=(lane>>4)*4+reg -> reduce across lane&15
#pragma unroll
  for (int m = 0; m < 4; ++m)
#pragma unroll
    for (int r = 0; r < 4; ++r) {
      float v = rowacc[m][r];
      v += __shfl_xor(v, 1);
      v += __shfl_xor(v, 2);
      v += __shfl_xor(v, 4);
      v += __shfl_xor(v, 8);
      if (lm == 0)
        atomicAdd(&rowsum[brow * BM + wm * 64 + m * 16 + lk * 4 + r], v);
    }
  // col sums: col=lane&15 -> reduce across lane>>4
#pragma unroll
  for (int n = 0; n < 4; ++n) {
    float v = colacc[n];
    v += __shfl_xor(v, 16);
    v += __shfl_xor(v, 32);
    if (lk == 0)
      atomicAdd(&colsum[bcol * BN + wn * 64 + n * 16 + lm], v);
  }
}

// ---------------- fallback (reg-staging, no ws bf16 buffers) ----------------
__global__ __launch_bounds__(THREADS) void clip_main_fb(
    const float* __restrict__ X, const float* __restrict__ Y,
    float* __restrict__ rowsum, float* __restrict__ colsum,
    float* __restrict__ diagsum) {
  __shared__ __align__(16) unsigned char smem[2 * BM * BK * 2];
  unsigned char* smA = smem;
  unsigned char* smB = smem + BM * BK * 2;

  const int tid = threadIdx.x;
  const int bid = blockIdx.x;
  const int swz = (bid & 7) * 2048 + (bid >> 3);
  const int brow = swz >> 7;
  const int bcol = swz & 127;

  const float* xb = X + (size_t)brow * BM * DD;
  const float* yb = Y + (size_t)bcol * BN * DD;

  const int wid = tid >> 6, lane = tid & 63;
  const int wm = wid >> 1, wn = wid & 1;
  const int lm = lane & 15, lk = lane >> 4;

  f32x4 acc[4][4] = {};

  for (int ks = 0; ks < NKS; ++ks) {
    const int kbase = ks * BK;
    if (ks) __syncthreads();
#pragma unroll
    for (int i = 0; i < 4; ++i) {
      const int c = tid + i * THREADS;
      const int row = c >> 3, slot = c & 7;
      const int boff = row * (BK * 2) + ((slot << 4) ^ ((row & 7) << 4));
      const float* ga = xb + row * DD + kbase + (slot << 3);
      float4 a0 = *(const float4*)ga;
      float4 a1 = *(const float4*)(ga + 4);
      uint4 pa = { pkbf(a0.x, a0.y), pkbf(a0.z, a0.w),
                   pkbf(a1.x, a1.y), pkbf(a1.z, a1.w) };
      *(uint4*)(smA + boff) = pa;
      const float* gb = yb + row * DD + kbase + (slot << 3);
      float4 b0 = *(const float4*)gb;
      float4 b1 = *(const float4*)(gb + 4);
      uint4 pb = { pkbf(b0.x, b0.y), pkbf(b0.z, b0.w),
                   pkbf(b1.x, b1.y), pkbf(b1.z, b1.w) };
      *(uint4*)(smB + boff) = pb;
    }
    __syncthreads();

#pragma unroll
    for (int kk = 0; kk < 2; ++kk) {
      const int kboff = kk * 64 + lk * 16;
      bf16x8 a[4], b[4];
#pragma unroll
      for (int m = 0; m < 4; ++m) {
        const int row = wm * 64 + m * 16 + lm;
        a[m] = *(const bf16x8*)(smA + row * (BK * 2) + (kboff ^ ((row & 7) << 4)));
      }
#pragma unroll
      for (int n = 0; n < 4; ++n) {
        const int row = wn * 64 + n * 16 + lm;
        b[n] = *(const bf16x8*)(smB + row * (BK * 2) + (kboff ^ ((row & 7) << 4)));
      }
#pragma unroll
      for (int m = 0; m < 4; ++m)
#pragma unroll
        for (int n = 0; n < 4; ++n)
          acc[m][n] = __builtin_amdgcn_mfma_f32_16x16x32_bf16(a[m], b[n], acc[m][n], 0, 0, 0);
    }
  }

  float rowacc[4][4];
  float colacc[4];
#pragma unroll
  for (int m = 0; m < 4; ++m)
#pragma unroll
    for (int r = 0; r < 4; ++r) rowacc[m][r] = 0.f;
#pragma unroll
  for (int n = 0; n < 4; ++n) colacc[n] = 0.f;

  const float negC = -(SHIFT_C * LOG2E);
#pragma unroll
  for (int m = 0; m < 4; ++m)
#pragma unroll
    for (int n = 0; n < 4; ++n)
#pragma unroll
      for (int r = 0; r < 4; ++r) {
        float e = EXP2F(__builtin_fmaf(acc[m][n][r], LOG2E, negC));
        rowacc[m][r] += e;
        colacc[n] += e;
      }

  if (brow == bcol && wm == wn) {
    float dsum = 0.f;
#pragma unroll
    for (int m = 0; m < 4; ++m)
#pragma unroll
      for (int n = 0; n < 4; ++n)
#pragma unroll
        for (int r = 0; r < 4; ++r) {
          const int rr = m * 16 + lk * 4 + r;
          const int cc = n * 16 + lm;
          if (rr == cc) dsum += acc[m][n][r];
        }
    dsum += __shfl_xor(dsum, 1);
    dsum += __shfl_xor(dsum, 2);
    dsum += __shfl_xor(dsum, 4);
    dsum += __shfl_xor(dsum, 8);
    dsum += __shfl_xor(dsum, 16);
    dsum += __shfl_xor(dsum, 32);
    if (lane == 0) atomicAdd(diagsum, dsum);
  }

#pragma unroll
  for (int m = 0; m < 4; ++m)
#pragma unroll
    for (int r = 0; r < 4; ++r) {
      float v = rowacc[m][r];
      v += __shfl_xor(v, 1);
      v += __shfl_xor(v, 2);
      v += __shfl_xor(v, 4);
      v += __shfl_xor(v, 8);
      if (lm == 0)
        atomicAdd(&rowsum[brow * BM + wm * 64 + m * 16 + lk * 4 + r], v);
    }
#pragma unroll
  for (int n = 0; n < 4; ++n) {
    float v = colacc[n];
    v += __shfl_xor(v, 16);
    v += __shfl_xor(v, 32);
    if (lk == 0)
      atomicAdd(&colsum[bcol * BN + wn * 64 + n * 16 + lm], v);
  }
}

__global__ __launch_bounds__(256) void clip_final(
    const float* __restrict__ rowsum, const float* __restrict__ colsum,
    const float* __restrict__ diagsum, float* __restrict__ out) {
  __shared__ double sdata[256];
  double s = 0.0;
  for (int i = threadIdx.x; i < NN; i += 256)
    s += (double)logf(rowsum[i]) + (double)logf(colsum[i]);
  sdata[threadIdx.x] = s;
  __syncthreads();
  for (int st = 128; st > 0; st >>= 1) {
    if ((int)threadIdx.x < st) sdata[threadIdx.x] += sdata[threadIdx.x + st];
    __syncthreads();
  }
  if (threadIdx.x == 0) {
    double loss = (double)SHIFT_C + sdata[0] * 0.5 / (double)NN
                - (double)diagsum[0] / (double)NN;
    out[0] = (float)loss;
  }
}

extern "C" void kernel_launch(void* const* d_in, const int* in_sizes, int n_in,
                              void* d_out, int out_size, void* d_ws, size_t ws_size,
                              hipStream_t stream) {
  const float* X = (const float*)d_in[0];
  const float* Y = (const float*)d_in[1];

  const size_t bf16_bytes = (size_t)2 * NN * DD * sizeof(unsigned short);  // 16 MB
  const size_t stats_bytes = (size_t)(2 * NN + 1) * sizeof(float);

  if (ws_size >= bf16_bytes + stats_bytes) {
    unsigned short* Xb = (unsigned short*)d_ws;
    unsigned short* Yb = Xb + (size_t)NN * DD;
    float* rowsum = (float*)((unsigned char*)d_ws + bf16_bytes);
    float* colsum = rowsum + NN;
    float* diagsum = colsum + NN;

    hipMemsetAsync(rowsum, 0, stats_bytes, stream);
    cvt_kernel<<<dim3(2 * NN * DD / 8 / 256), dim3(256), 0, stream>>>(X, Y, Xb, Yb);
    clip_gemm<<<dim3((NN / BM) * (NN / BN)), dim3(THREADS), 0, stream>>>(
        Xb, Yb, rowsum, colsum, diagsum);
    clip_final<<<dim3(1), dim3(256), 0, stream>>>(rowsum, colsum, diagsum, (float*)d_out);
  } else {
    float* rowsum = (float*)d_ws;
    float* colsum = rowsum + NN;
    float* diagsum = colsum + NN;
    hipMemsetAsync(d_ws, 0, stats_bytes, stream);
    clip_main_fb<<<dim3((NN / BM) * (NN / BN)), dim3(THREADS), 0, stream>>>(
        X, Y, rowsum, colsum, diagsum);
    clip_final<<<dim3(1), dim3(256), 0, stream>>>(rowsum, colsum, diagsum, (float*)d_out);
  }
}

// Round 3
// 285.597 us; speedup vs baseline: 2.1357x; 1.2703x over previous
//
#include <hip/hip_runtime.h>
#include <hip/hip_bf16.h>

#define NN 16384
#define DD 256
#define BM 128
#define BN 128
#define BK 64
#define NKS (DD / BK)
#define THREADS 256
#define SHIFT_C 64.0f
#define LOG2E 1.4426950408889634f

typedef __attribute__((ext_vector_type(4))) float f32x4;
typedef __attribute__((ext_vector_type(8))) short bf16x8;

#if __has_builtin(__builtin_amdgcn_exp2f)
#define EXP2F(x) __builtin_amdgcn_exp2f(x)
#else
#define EXP2F(x) exp2f(x)
#endif

__device__ __forceinline__ unsigned pkbf(float a, float b) {
  float2 t; t.x = a; t.y = b;
  __hip_bfloat162 h = __float22bfloat162_rn(t);
  union { __hip_bfloat162 h; unsigned u; } cv;
  cv.h = h;
  return cv.u;
}

// ---------------- pre-convert f32 -> bf16 ----------------
__global__ __launch_bounds__(256) void cvt_kernel(
    const float* __restrict__ X, const float* __restrict__ Y,
    unsigned short* __restrict__ Xb, unsigned short* __restrict__ Yb) {
  const int groups_per_arr = NN * DD / 8;  // 524288 groups of 8 elems
  int g = blockIdx.x * 256 + threadIdx.x;
  const float* src;
  unsigned short* dst;
  if (g < groups_per_arr) { src = X; dst = Xb; }
  else { src = Y; dst = Yb; g -= groups_per_arr; }
  float4 a = ((const float4*)src)[(size_t)g * 2];
  float4 b = ((const float4*)src)[(size_t)g * 2 + 1];
  uint4 p = { pkbf(a.x, a.y), pkbf(a.z, a.w), pkbf(b.x, b.y), pkbf(b.z, b.w) };
  ((uint4*)dst)[g] = p;
}

// ---------------- main fused GEMM + softmax-stats ----------------
// T2-style swizzle with global_load_lds (rule #21): LDS dest stays linear,
// global SOURCE is pre-swizzled (16B slot ^= row&7), ds_read applies the
// same XOR. Removes the 16-way bank conflict of stride-128B row-major LDS.
__global__ __launch_bounds__(THREADS) void clip_gemm(
    const unsigned short* __restrict__ Xb, const unsigned short* __restrict__ Yb,
    float* __restrict__ rowsum, float* __restrict__ colsum,
    float* __restrict__ diagsum) {
  __shared__ __align__(16) unsigned char smA[BM * BK * 2];
  __shared__ __align__(16) unsigned char smB[BN * BK * 2];

  const int tid = threadIdx.x;
  const int bid = blockIdx.x;
  // 2-level XCD-aware swizzle: each XCD owns brows [16k,16k+16); within XCD,
  // 16x16-tile supertiles so X-slice (2MB) + Y-slice (2MB) are both L2-resident.
  const int xcd = bid & 7;
  const int t = bid >> 3;       // 0..2047 within XCD
  const int st = t >> 8;        // 8 supertiles (column panels of 16 bcols)
  const int idx = t & 255;
  const int brow = xcd * 16 + (idx >> 4);
  const int bcol = st * 16 + (idx & 15);

  const unsigned short* xb = Xb + (size_t)brow * BM * DD;
  const unsigned short* yb = Yb + (size_t)bcol * BN * DD;

  const int wid = tid >> 6, lane = tid & 63;
  const int wm = wid >> 1, wn = wid & 1;
  const int lm = lane & 15, lk = lane >> 4;

  const int srow0 = wid * 8 + (lane >> 3);   // staging row base (per thread)
  // source k-offset with inverse swizzle: slot ^ (row&7); row&7 == lane>>3
  const int skoff = (((lane & 7) ^ (lane >> 3)) << 3);
  const int sldso = wid * 1024 + lane * 16;  // linear staging LDS byte offset

  f32x4 acc[4][4] = {};

#define STAGE(ks)                                                              \
  {                                                                            \
    _Pragma("unroll")                                                          \
    for (int i = 0; i < 4; ++i) {                                              \
      const int row = i * 32 + srow0;                                          \
      __builtin_amdgcn_global_load_lds(                                        \
          (const __attribute__((address_space(1))) unsigned*)(xb + (size_t)row * DD + (ks) * BK + skoff), \
          (__attribute__((address_space(3))) unsigned*)(smA + i * 4096 + sldso), 16, 0, 0); \
      __builtin_amdgcn_global_load_lds(                                        \
          (const __attribute__((address_space(1))) unsigned*)(yb + (size_t)row * DD + (ks) * BK + skoff), \
          (__attribute__((address_space(3))) unsigned*)(smB + i * 4096 + sldso), 16, 0, 0); \
    }                                                                          \
  }

  STAGE(0);
  const int rxor = (lm & 7) << 4;  // swizzle XOR for ds_read (row&7 == lm&7)
  for (int ks = 0; ks < NKS; ++ks) {
    __syncthreads();  // drains vmcnt -> staged tile visible
#pragma unroll
    for (int kk = 0; kk < 2; ++kk) {
      const int kboff = (kk * 64 + lk * 16) ^ rxor;
      bf16x8 a[4], b[4];
#pragma unroll
      for (int m = 0; m < 4; ++m)
        a[m] = *(const bf16x8*)(smA + (wm * 64 + m * 16 + lm) * (BK * 2) + kboff);
#pragma unroll
      for (int n = 0; n < 4; ++n)
        b[n] = *(const bf16x8*)(smB + (wn * 64 + n * 16 + lm) * (BK * 2) + kboff);
#pragma unroll
      for (int m = 0; m < 4; ++m)
#pragma unroll
        for (int n = 0; n < 4; ++n)
          acc[m][n] = __builtin_amdgcn_mfma_f32_16x16x32_bf16(a[m], b[n], acc[m][n], 0, 0, 0);
    }
    if (ks < NKS - 1) {
      __syncthreads();  // all reads of this tile done before overwrite
      STAGE(ks + 1);
    }
  }
#undef STAGE

  // ---- fused softmax-statistics epilogue ----
  float rowacc[4][4];
  float colacc[4];
#pragma unroll
  for (int m = 0; m < 4; ++m)
#pragma unroll
    for (int r = 0; r < 4; ++r) rowacc[m][r] = 0.f;
#pragma unroll
  for (int n = 0; n < 4; ++n) colacc[n] = 0.f;

  const float negC = -(SHIFT_C * LOG2E);
#pragma unroll
  for (int m = 0; m < 4; ++m)
#pragma unroll
    for (int n = 0; n < 4; ++n)
#pragma unroll
      for (int r = 0; r < 4; ++r) {
        float e = EXP2F(__builtin_fmaf(acc[m][n][r], LOG2E, negC));
        rowacc[m][r] += e;
        colacc[n] += e;
      }

  // diagonal logits (only diagonal blocks, only diagonal waves)
  if (brow == bcol && wm == wn) {
    float dsum = 0.f;
#pragma unroll
    for (int m = 0; m < 4; ++m)
#pragma unroll
      for (int n = 0; n < 4; ++n)
#pragma unroll
        for (int r = 0; r < 4; ++r) {
          const int rr = m * 16 + lk * 4 + r;
          const int cc = n * 16 + lm;
          if (rr == cc) dsum += acc[m][n][r];
        }
    dsum += __shfl_xor(dsum, 1);
    dsum += __shfl_xor(dsum, 2);
    dsum += __shfl_xor(dsum, 4);
    dsum += __shfl_xor(dsum, 8);
    dsum += __shfl_xor(dsum, 16);
    dsum += __shfl_xor(dsum, 32);
    if (lane == 0) atomicAdd(diagsum, dsum);
  }

  // row sums: C/D layout row=(lane>>4)*4+reg -> reduce across lane&15
#pragma unroll
  for (int m = 0; m < 4; ++m)
#pragma unroll
    for (int r = 0; r < 4; ++r) {
      float v = rowacc[m][r];
      v += __shfl_xor(v, 1);
      v += __shfl_xor(v, 2);
      v += __shfl_xor(v, 4);
      v += __shfl_xor(v, 8);
      if (lm == 0)
        atomicAdd(&rowsum[brow * BM + wm * 64 + m * 16 + lk * 4 + r], v);
    }
  // col sums: col=lane&15 -> reduce across lane>>4
#pragma unroll
  for (int n = 0; n < 4; ++n) {
    float v = colacc[n];
    v += __shfl_xor(v, 16);
    v += __shfl_xor(v, 32);
    if (lk == 0)
      atomicAdd(&colsum[bcol * BN + wn * 64 + n * 16 + lm], v);
  }
}

// ---------------- fallback (reg-staging, no ws bf16 buffers) ----------------
__global__ __launch_bounds__(THREADS) void clip_main_fb(
    const float* __restrict__ X, const float* __restrict__ Y,
    float* __restrict__ rowsum, float* __restrict__ colsum,
    float* __restrict__ diagsum) {
  __shared__ __align__(16) unsigned char smem[2 * BM * BK * 2];
  unsigned char* smA = smem;
  unsigned char* smB = smem + BM * BK * 2;

  const int tid = threadIdx.x;
  const int bid = blockIdx.x;
  const int swz = (bid & 7) * 2048 + (bid >> 3);
  const int brow = swz >> 7;
  const int bcol = swz & 127;

  const float* xb = X + (size_t)brow * BM * DD;
  const float* yb = Y + (size_t)bcol * BN * DD;

  const int wid = tid >> 6, lane = tid & 63;
  const int wm = wid >> 1, wn = wid & 1;
  const int lm = lane & 15, lk = lane >> 4;

  f32x4 acc[4][4] = {};

  for (int ks = 0; ks < NKS; ++ks) {
    const int kbase = ks * BK;
    if (ks) __syncthreads();
#pragma unroll
    for (int i = 0; i < 4; ++i) {
      const int c = tid + i * THREADS;
      const int row = c >> 3, slot = c & 7;
      const int boff = row * (BK * 2) + ((slot << 4) ^ ((row & 7) << 4));
      const float* ga = xb + row * DD + kbase + (slot << 3);
      float4 a0 = *(const float4*)ga;
      float4 a1 = *(const float4*)(ga + 4);
      uint4 pa = { pkbf(a0.x, a0.y), pkbf(a0.z, a0.w),
                   pkbf(a1.x, a1.y), pkbf(a1.z, a1.w) };
      *(uint4*)(smA + boff) = pa;
      const float* gb = yb + row * DD + kbase + (slot << 3);
      float4 b0 = *(const float4*)gb;
      float4 b1 = *(const float4*)(gb + 4);
      uint4 pb = { pkbf(b0.x, b0.y), pkbf(b0.z, b0.w),
                   pkbf(b1.x, b1.y), pkbf(b1.z, b1.w) };
      *(uint4*)(smB + boff) = pb;
    }
    __syncthreads();

#pragma unroll
    for (int kk = 0; kk < 2; ++kk) {
      const int kboff = kk * 64 + lk * 16;
      bf16x8 a[4], b[4];
#pragma unroll
      for (int m = 0; m < 4; ++m) {
        const int row = wm * 64 + m * 16 + lm;
        a[m] = *(const bf16x8*)(smA + row * (BK * 2) + (kboff ^ ((row & 7) << 4)));
      }
#pragma unroll
      for (int n = 0; n < 4; ++n) {
        const int row = wn * 64 + n * 16 + lm;
        b[n] = *(const bf16x8*)(smB + row * (BK * 2) + (kboff ^ ((row & 7) << 4)));
      }
#pragma unroll
      for (int m = 0; m < 4; ++m)
#pragma unroll
        for (int n = 0; n < 4; ++n)
          acc[m][n] = __builtin_amdgcn_mfma_f32_16x16x32_bf16(a[m], b[n], acc[m][n], 0, 0, 0);
    }
  }

  float rowacc[4][4];
  float colacc[4];
#pragma unroll
  for (int m = 0; m < 4; ++m)
#pragma unroll
    for (int r = 0; r < 4; ++r) rowacc[m][r] = 0.f;
#pragma unroll
  for (int n = 0; n < 4; ++n) colacc[n] = 0.f;

  const float negC = -(SHIFT_C * LOG2E);
#pragma unroll
  for (int m = 0; m < 4; ++m)
#pragma unroll
    for (int n = 0; n < 4; ++n)
#pragma unroll
      for (int r = 0; r < 4; ++r) {
        float e = EXP2F(__builtin_fmaf(acc[m][n][r], LOG2E, negC));
        rowacc[m][r] += e;
        colacc[n] += e;
      }

  if (brow == bcol && wm == wn) {
    float dsum = 0.f;
#pragma unroll
    for (int m = 0; m < 4; ++m)
#pragma unroll
      for (int n = 0; n < 4; ++n)
#pragma unroll
        for (int r = 0; r < 4; ++r) {
          const int rr = m * 16 + lk * 4 + r;
          const int cc = n * 16 + lm;
          if (rr == cc) dsum += acc[m][n][r];
        }
    dsum += __shfl_xor(dsum, 1);
    dsum += __shfl_xor(dsum, 2);
    dsum += __shfl_xor(dsum, 4);
    dsum += __shfl_xor(dsum, 8);
    dsum += __shfl_xor(dsum, 16);
    dsum += __shfl_xor(dsum, 32);
    if (lane == 0) atomicAdd(diagsum, dsum);
  }

#pragma unroll
  for (int m = 0; m < 4; ++m)
#pragma unroll
    for (int r = 0; r < 4; ++r) {
      float v = rowacc[m][r];
      v += __shfl_xor(v, 1);
      v += __shfl_xor(v, 2);
      v += __shfl_xor(v, 4);
      v += __shfl_xor(v, 8);
      if (lm == 0)
        atomicAdd(&rowsum[brow * BM + wm * 64 + m * 16 + lk * 4 + r], v);
    }
#pragma unroll
  for (int n = 0; n < 4; ++n) {
    float v = colacc[n];
    v += __shfl_xor(v, 16);
    v += __shfl_xor(v, 32);
    if (lk == 0)
      atomicAdd(&colsum[bcol * BN + wn * 64 + n * 16 + lm], v);
  }
}

__global__ __launch_bounds__(256) void clip_final(
    const float* __restrict__ rowsum, const float* __restrict__ colsum,
    const float* __restrict__ diagsum, float* __restrict__ out) {
  __shared__ double sdata[256];
  double s = 0.0;
  for (int i = threadIdx.x; i < NN; i += 256)
    s += (double)logf(rowsum[i]) + (double)logf(colsum[i]);
  sdata[threadIdx.x] = s;
  __syncthreads();
  for (int st = 128; st > 0; st >>= 1) {
    if ((int)threadIdx.x < st) sdata[threadIdx.x] += sdata[threadIdx.x + st];
    __syncthreads();
  }
  if (threadIdx.x == 0) {
    double loss = (double)SHIFT_C + sdata[0] * 0.5 / (double)NN
                - (double)diagsum[0] / (double)NN;
    out[0] = (float)loss;
  }
}

extern "C" void kernel_launch(void* const* d_in, const int* in_sizes, int n_in,
                              void* d_out, int out_size, void* d_ws, size_t ws_size,
                              hipStream_t stream) {
  const float* X = (const float*)d_in[0];
  const float* Y = (const float*)d_in[1];

  const size_t bf16_bytes = (size_t)2 * NN * DD * sizeof(unsigned short);  // 16 MB
  const size_t stats_bytes = (size_t)(2 * NN + 1) * sizeof(float);

  if (ws_size >= bf16_bytes + stats_bytes) {
    unsigned short* Xb = (unsigned short*)d_ws;
    unsigned short* Yb = Xb + (size_t)NN * DD;
    float* rowsum = (float*)((unsigned char*)d_ws + bf16_bytes);
    float* colsum = rowsum + NN;
    float* diagsum = colsum + NN;

    hipMemsetAsync(rowsum, 0, stats_bytes, stream);
    cvt_kernel<<<dim3(2 * NN * DD / 8 / 256), dim3(256), 0, stream>>>(X, Y, Xb, Yb);
    clip_gemm<<<dim3((NN / BM) * (NN / BN)), dim3(THREADS), 0, stream>>>(
        Xb, Yb, rowsum, colsum, diagsum);
    clip_final<<<dim3(1), dim3(256), 0, stream>>>(rowsum, colsum, diagsum, (float*)d_out);
  } else {
    float* rowsum = (float*)d_ws;
    float* colsum = rowsum + NN;
    float* diagsum = colsum + NN;
    hipMemsetAsync(d_ws, 0, stats_bytes, stream);
    clip_main_fb<<<dim3((NN / BM) * (NN / BN)), dim3(THREADS), 0, stream>>>(
        X, Y, rowsum, colsum, diagsum);
    clip_final<<<dim3(1), dim3(256), 0, stream>>>(rowsum, colsum, diagsum, (float*)d_out);
  }
}